// Round 3
// baseline (305.369 us; speedup 1.0000x reference)
//
#include <hip/hip_runtime.h>
#include <hip/hip_bf16.h>

// Problem: X[64][1024][128] fp32. out = mean_{b,s,t} (cos(x_bs, x_bt) - 1)^2
// Identity: sum_{s,t}(S_st-1)^2 = ||G||_F^2 - 2*||v||^2 + S^2, where
//   G = Xn^T Xn (128x128 feature Gram per batch), v = sum_s xn_s.
// -> 2.15 GFLOP instead of 17.2 GFLOP; no SxS matrix.
//
// ROUND-3 FIX: d_out is FLOAT (reference returns fp32; rounds 1-2 wrote bf16
// into a zeroed fp32 slot -> word 0x00003F81 ~ 0 -> absmax == ref. Root cause
// of both failures.) Also: Gram accumulated via atomicAdd into one 4 MB
// per-batch buffer -> ws requirement only ~4.3 MB (ws_size was unverified).

#define BATCH  64
#define SEQ    1024
#define DIM    128
#define KSPLIT 8
#define ROWS_PER_WG (SEQ / KSPLIT)    // 128 rows per workgroup
#define CHUNK  32                     // rows staged in LDS per step
#define NCHUNK (ROWS_PER_WG / CHUNK)  // 4
#define LDSW   (DIM + 4)              // pad: keeps 16B align, breaks pow2 stride
#define GSZ    (DIM * DIM)            // 16384 floats per batch Gram

// ws layout: [0, 4MB) G[64][128][128]; [4MB, +32KB) vglob[64][128]; then acc[4].
#define G_OFF    0
#define V_OFF    ((size_t)BATCH * GSZ)               // floats
#define ACC_OFF  (V_OFF + (size_t)BATCH * DIM)       // floats
#define ZTOTAL   (ACC_OFF + 4)                       // floats to zero

// ---- k0: zero G + vglob + acc ----
__global__ __launch_bounds__(256)
void k0_zero(float* __restrict__ ws) {
    size_t i = (size_t)blockIdx.x * 256 + threadIdx.x;
    if (i < ZTOTAL) ws[i] = 0.0f;
}

// ---- k1: one wg = (batch b, k-split ks). Normalize 128 rows, accumulate
//      into per-batch G via atomicAdd, and per-batch column-sum v. ----
__global__ __launch_bounds__(256, 2)
void k1_gram(const float* __restrict__ X, float* __restrict__ G,
             float* __restrict__ vglob) {
    __shared__ __align__(16) float lds[2][CHUNK][LDSW];  // 33.8 KB

    const int t  = threadIdx.x;
    const int wg = blockIdx.x;
    const int b  = wg >> 3;          // / KSPLIT
    const int ks = wg & (KSPLIT - 1);
    const int r  = t >> 3;    // staging row 0..31
    const int q  = t & 7;     // staging float4 phase 0..7
    const int ti = t >> 4;    // gram tile row 0..15
    const int tj = t & 15;    // gram tile col 0..15

    const float* Xbase = X + (size_t)(b * SEQ + ks * ROWS_PER_WG) * DIM;

    float acc[8][8];
#pragma unroll
    for (int i = 0; i < 8; ++i)
#pragma unroll
        for (int j = 0; j < 8; ++j) acc[i][j] = 0.0f;

    float vreg[16];
#pragma unroll
    for (int k = 0; k < 16; ++k) vreg[k] = 0.0f;

    float4 g4[4];

    // prologue: load + normalize + stage chunk 0 into buffer 0
    {
        const float4* rowp = (const float4*)(Xbase + (size_t)r * DIM);
#pragma unroll
        for (int k = 0; k < 4; ++k) g4[k] = rowp[q + 8 * k];
        float ssq = 0.0f;
#pragma unroll
        for (int k = 0; k < 4; ++k)
            ssq += g4[k].x * g4[k].x + g4[k].y * g4[k].y +
                   g4[k].z * g4[k].z + g4[k].w * g4[k].w;
        ssq += __shfl_xor(ssq, 1, 8);
        ssq += __shfl_xor(ssq, 2, 8);
        ssq += __shfl_xor(ssq, 4, 8);
        float inv = rsqrtf(fmaxf(ssq, 1e-24f));
#pragma unroll
        for (int k = 0; k < 4; ++k) {
            float4 n;
            n.x = g4[k].x * inv; n.y = g4[k].y * inv;
            n.z = g4[k].z * inv; n.w = g4[k].w * inv;
            vreg[k * 4 + 0] += n.x; vreg[k * 4 + 1] += n.y;
            vreg[k * 4 + 2] += n.z; vreg[k * 4 + 3] += n.w;
            *(float4*)&lds[0][r][(q + 8 * k) * 4] = n;
        }
    }
    __syncthreads();

    for (int c = 0; c < NCHUNK; ++c) {
        const int cur = c & 1;
        // issue next chunk's global loads early (overlap with compute)
        if (c + 1 < NCHUNK) {
            const float4* rowp =
                (const float4*)(Xbase + (size_t)((c + 1) * CHUNK + r) * DIM);
#pragma unroll
            for (int k = 0; k < 4; ++k) g4[k] = rowp[q + 8 * k];
        }
        // compute on buffer cur: acc[i][j] += xn[s][ti*8+i] * xn[s][tj*8+j]
        for (int s = 0; s < CHUNK; ++s) {
            const float4 a0 = *(const float4*)&lds[cur][s][ti * 8];
            const float4 a1 = *(const float4*)&lds[cur][s][ti * 8 + 4];
            const float4 b0 = *(const float4*)&lds[cur][s][tj * 8];
            const float4 b1 = *(const float4*)&lds[cur][s][tj * 8 + 4];
            const float A[8] = {a0.x, a0.y, a0.z, a0.w, a1.x, a1.y, a1.z, a1.w};
            const float B[8] = {b0.x, b0.y, b0.z, b0.w, b1.x, b1.y, b1.z, b1.w};
#pragma unroll
            for (int i = 0; i < 8; ++i)
#pragma unroll
                for (int j = 0; j < 8; ++j)
                    acc[i][j] = fmaf(A[i], B[j], acc[i][j]);
        }
        // normalize + stage next chunk into the other buffer
        if (c + 1 < NCHUNK) {
            float ssq = 0.0f;
#pragma unroll
            for (int k = 0; k < 4; ++k)
                ssq += g4[k].x * g4[k].x + g4[k].y * g4[k].y +
                       g4[k].z * g4[k].z + g4[k].w * g4[k].w;
            ssq += __shfl_xor(ssq, 1, 8);
            ssq += __shfl_xor(ssq, 2, 8);
            ssq += __shfl_xor(ssq, 4, 8);
            float inv = rsqrtf(fmaxf(ssq, 1e-24f));
#pragma unroll
            for (int k = 0; k < 4; ++k) {
                float4 n;
                n.x = g4[k].x * inv; n.y = g4[k].y * inv;
                n.z = g4[k].z * inv; n.w = g4[k].w * inv;
                vreg[k * 4 + 0] += n.x; vreg[k * 4 + 1] += n.y;
                vreg[k * 4 + 2] += n.z; vreg[k * 4 + 3] += n.w;
                *(float4*)&lds[1 - cur][r][(q + 8 * k) * 4] = n;
            }
        }
        __syncthreads();
    }

    // accumulate this wg's 8x8 tile into per-batch Gram (8-way wg contention
    // spread over 16K addresses -> negligible serialization)
    float* gb = G + (size_t)b * GSZ + (size_t)(ti * 8) * DIM + tj * 8;
#pragma unroll
    for (int i = 0; i < 8; ++i)
#pragma unroll
        for (int j = 0; j < 8; ++j)
            atomicAdd(&gb[(size_t)i * DIM + j], acc[i][j]);

    // reduce vreg (per-thread column partials) across the block via LDS
    __syncthreads();
    float* scratch = (float*)lds;          // 256*16 floats = 16 KB, fits
#pragma unroll
    for (int k = 0; k < 16; ++k) scratch[t * 16 + k] = vreg[k];
    __syncthreads();
    if (t < DIM) {
        // column t = 4*(q + 8*k) + j  ->  q=(t>>2)&7, k=t>>5, j=t&3
        const int qq = (t >> 2) & 7, kk = t >> 5, jj = t & 3;
        float v = 0.0f;
        for (int m = 0; m < 32; ++m)
            v += scratch[(m * 8 + qq) * 16 + kk * 4 + jj];
        atomicAdd(&vglob[b * DIM + t], v);
    }
}

// ---- k2: per (batch, quarter): accumulate ||G_b||_F^2 (and ||v_b||^2 on
//      quarter 0) into acc via atomics. ----
__global__ __launch_bounds__(256, 2)
void k2_reduce(const float* __restrict__ G, const float* __restrict__ vglob,
               float* __restrict__ acc) {
    const int t = threadIdx.x;
    const int b = blockIdx.x >> 2;
    const int quarter = blockIdx.x & 3;
    const float4* gb = (const float4*)(G + (size_t)b * GSZ);

    float sG = 0.0f;
#pragma unroll
    for (int kk = 0; kk < 4; ++kk) {
        float4 g = gb[quarter * 1024 + kk * 256 + t];
        sG += g.x * g.x + g.y * g.y + g.z * g.z + g.w * g.w;
    }
    float sV = 0.0f;
    if (quarter == 0 && t < DIM) {
        float vv = vglob[b * DIM + t];
        sV = vv * vv;
    }
#pragma unroll
    for (int m = 1; m < 64; m <<= 1) {
        sG += __shfl_xor(sG, m);
        sV += __shfl_xor(sV, m);
    }
    __shared__ float wq[8];
    if ((t & 63) == 0) { wq[t >> 6] = sG; wq[4 + (t >> 6)] = sV; }
    __syncthreads();
    if (t == 0) {
        atomicAdd(&acc[0], wq[0] + wq[1] + wq[2] + wq[3]);
        if (quarter == 0) atomicAdd(&acc[1], wq[4] + wq[5] + wq[6] + wq[7]);
    }
}

// ---- k3: result = (sumG2 - 2*sumV2)/(B*S^2) + 1, written as FP32 ----
__global__ void k3_final(const float* __restrict__ acc,
                         float* __restrict__ out) {
    out[0] = (acc[0] - 2.0f * acc[1]) * (1.0f / 67108864.0f) + 1.0f;
}

extern "C" void kernel_launch(void* const* d_in, const int* in_sizes, int n_in,
                              void* d_out, int out_size, void* d_ws, size_t ws_size,
                              hipStream_t stream) {
    const float* X = (const float*)d_in[0];
    float* ws = (float*)d_ws;   // needs ZTOTAL*4 ~ 4.23 MB
    float* G     = ws + G_OFF;
    float* vglob = ws + V_OFF;
    float* acc   = ws + ACC_OFF;

    k0_zero<<<(int)((ZTOTAL + 255) / 256), 256, 0, stream>>>(ws);
    k1_gram<<<BATCH * KSPLIT, 256, 0, stream>>>(X, G, vglob);
    k2_reduce<<<BATCH * 4, 256, 0, stream>>>(G, vglob, acc);
    k3_final<<<1, 1, 0, stream>>>(acc, (float*)d_out);
}

// Round 4
// 112.183 us; speedup vs baseline: 2.7221x; 2.7221x over previous
//
#include <hip/hip_runtime.h>
#include <hip/hip_bf16.h>

// Problem: X[64][1024][128] fp32. out = mean_{b,s,t} (cos(x_bs, x_bt) - 1)^2
// Identity: sum_{s,t}(S_st-1)^2 = ||G||_F^2 - 2*||v||^2 + S^2, where
//   G = Xn^T Xn (128x128 feature Gram per batch), v = sum_s xn_s.
// -> 2.15 GFLOP instead of 17.2 GFLOP; no SxS matrix.
//
// ROUND-4: round-3 passed (absmax 0.0) but k1 was an atomic-write storm:
// 8.4M device-scope fp32 atomicAdds -> WRITE_SIZE 256 MB, VALUBusy 6.5%,
// 244 us. Replace with private per-wg partial Grams (plain coalesced float4
// stores, 32 MB total; ws usage ~32.1 MB which round-1/2 demonstrated is
// within ws_size) + k2 sums the 8 partials per batch before squaring.

#define BATCH  64
#define SEQ    1024
#define DIM    128
#define KSPLIT 8
#define ROWS_PER_WG (SEQ / KSPLIT)    // 128 rows per workgroup
#define CHUNK  32                     // rows staged in LDS per step
#define NCHUNK (ROWS_PER_WG / CHUNK)  // 4
#define LDSW   (DIM + 4)              // pad: keeps 16B align, breaks pow2 stride
#define GSZ    (DIM * DIM)            // 16384 floats per partial Gram

// ws layout (floats): [0, 8192) vglob[64][128]; [8192, 8196) acc;
//                     [16384, 16384 + 512*16384) gpart. Total ~32.1 MB.
#define V_OFF    0
#define ACC_OFF  8192
#define GP_OFF   16384
#define ZTOTAL   8196                 // floats to zero (vglob + acc only)

// ---- k0: zero vglob + acc ----
__global__ __launch_bounds__(256)
void k0_zero(float* __restrict__ ws) {
    int i = blockIdx.x * 256 + threadIdx.x;
    if (i < ZTOTAL) ws[i] = 0.0f;
}

// ---- k1: one wg = (batch b, k-split ks). Normalize 128 rows, accumulate
//      private partial Gram (no atomics) and per-batch column-sum v. ----
__global__ __launch_bounds__(256, 2)
void k1_gram(const float* __restrict__ X, float* __restrict__ gpart,
             float* __restrict__ vglob) {
    __shared__ __align__(16) float lds[2][CHUNK][LDSW];  // 33.8 KB

    const int t  = threadIdx.x;
    const int wg = blockIdx.x;
    const int b  = wg >> 3;          // / KSPLIT
    const int ks = wg & (KSPLIT - 1);
    const int r  = t >> 3;    // staging row 0..31
    const int q  = t & 7;     // staging float4 phase 0..7
    const int ti = t >> 4;    // gram tile row 0..15
    const int tj = t & 15;    // gram tile col 0..15

    const float* Xbase = X + (size_t)(b * SEQ + ks * ROWS_PER_WG) * DIM;

    float acc[8][8];
#pragma unroll
    for (int i = 0; i < 8; ++i)
#pragma unroll
        for (int j = 0; j < 8; ++j) acc[i][j] = 0.0f;

    float vreg[16];
#pragma unroll
    for (int k = 0; k < 16; ++k) vreg[k] = 0.0f;

    float4 g4[4];

    // prologue: load + normalize + stage chunk 0 into buffer 0
    {
        const float4* rowp = (const float4*)(Xbase + (size_t)r * DIM);
#pragma unroll
        for (int k = 0; k < 4; ++k) g4[k] = rowp[q + 8 * k];
        float ssq = 0.0f;
#pragma unroll
        for (int k = 0; k < 4; ++k)
            ssq += g4[k].x * g4[k].x + g4[k].y * g4[k].y +
                   g4[k].z * g4[k].z + g4[k].w * g4[k].w;
        ssq += __shfl_xor(ssq, 1, 8);
        ssq += __shfl_xor(ssq, 2, 8);
        ssq += __shfl_xor(ssq, 4, 8);
        float inv = rsqrtf(fmaxf(ssq, 1e-24f));
#pragma unroll
        for (int k = 0; k < 4; ++k) {
            float4 n;
            n.x = g4[k].x * inv; n.y = g4[k].y * inv;
            n.z = g4[k].z * inv; n.w = g4[k].w * inv;
            vreg[k * 4 + 0] += n.x; vreg[k * 4 + 1] += n.y;
            vreg[k * 4 + 2] += n.z; vreg[k * 4 + 3] += n.w;
            *(float4*)&lds[0][r][(q + 8 * k) * 4] = n;
        }
    }
    __syncthreads();

    for (int c = 0; c < NCHUNK; ++c) {
        const int cur = c & 1;
        // issue next chunk's global loads early (overlap with compute)
        if (c + 1 < NCHUNK) {
            const float4* rowp =
                (const float4*)(Xbase + (size_t)((c + 1) * CHUNK + r) * DIM);
#pragma unroll
            for (int k = 0; k < 4; ++k) g4[k] = rowp[q + 8 * k];
        }
        // compute on buffer cur: acc[i][j] += xn[s][ti*8+i] * xn[s][tj*8+j]
        for (int s = 0; s < CHUNK; ++s) {
            const float4 a0 = *(const float4*)&lds[cur][s][ti * 8];
            const float4 a1 = *(const float4*)&lds[cur][s][ti * 8 + 4];
            const float4 b0 = *(const float4*)&lds[cur][s][tj * 8];
            const float4 b1 = *(const float4*)&lds[cur][s][tj * 8 + 4];
            const float A[8] = {a0.x, a0.y, a0.z, a0.w, a1.x, a1.y, a1.z, a1.w};
            const float B[8] = {b0.x, b0.y, b0.z, b0.w, b1.x, b1.y, b1.z, b1.w};
#pragma unroll
            for (int i = 0; i < 8; ++i)
#pragma unroll
                for (int j = 0; j < 8; ++j)
                    acc[i][j] = fmaf(A[i], B[j], acc[i][j]);
        }
        // normalize + stage next chunk into the other buffer
        if (c + 1 < NCHUNK) {
            float ssq = 0.0f;
#pragma unroll
            for (int k = 0; k < 4; ++k)
                ssq += g4[k].x * g4[k].x + g4[k].y * g4[k].y +
                       g4[k].z * g4[k].z + g4[k].w * g4[k].w;
            ssq += __shfl_xor(ssq, 1, 8);
            ssq += __shfl_xor(ssq, 2, 8);
            ssq += __shfl_xor(ssq, 4, 8);
            float inv = rsqrtf(fmaxf(ssq, 1e-24f));
#pragma unroll
            for (int k = 0; k < 4; ++k) {
                float4 n;
                n.x = g4[k].x * inv; n.y = g4[k].y * inv;
                n.z = g4[k].z * inv; n.w = g4[k].w * inv;
                vreg[k * 4 + 0] += n.x; vreg[k * 4 + 1] += n.y;
                vreg[k * 4 + 2] += n.z; vreg[k * 4 + 3] += n.w;
                *(float4*)&lds[1 - cur][r][(q + 8 * k) * 4] = n;
            }
        }
        __syncthreads();
    }

    // write this wg's partial Gram to its private slot (coalesced, no atomics)
    float* gp = gpart + (size_t)wg * GSZ + (size_t)(ti * 8) * DIM + tj * 8;
#pragma unroll
    for (int i = 0; i < 8; ++i) {
        *(float4*)(gp + (size_t)i * DIM + 0) =
            make_float4(acc[i][0], acc[i][1], acc[i][2], acc[i][3]);
        *(float4*)(gp + (size_t)i * DIM + 4) =
            make_float4(acc[i][4], acc[i][5], acc[i][6], acc[i][7]);
    }

    // reduce vreg (per-thread column partials) across the block via LDS
    __syncthreads();
    float* scratch = (float*)lds;          // 256*16 floats = 16 KB, fits
#pragma unroll
    for (int k = 0; k < 16; ++k) scratch[t * 16 + k] = vreg[k];
    __syncthreads();
    if (t < DIM) {
        // column t = 4*(q + 8*k) + j  ->  q=(t>>2)&7, k=t>>5, j=t&3
        const int qq = (t >> 2) & 7, kk = t >> 5, jj = t & 3;
        float v = 0.0f;
        for (int m = 0; m < 32; ++m)
            v += scratch[(m * 8 + qq) * 16 + kk * 4 + jj];
        atomicAdd(&vglob[b * DIM + t], v);   // only 8K tiny atomics total
    }
}

// ---- k2: per (batch, quarter): sum 8 partial Grams, accumulate ||G||_F^2;
//      quarter 0 also accumulates ||v||^2. ----
__global__ __launch_bounds__(256, 2)
void k2_reduce(const float* __restrict__ gpart, const float* __restrict__ vglob,
               float* __restrict__ acc) {
    const int t = threadIdx.x;
    const int b = blockIdx.x >> 2;
    const int quarter = blockIdx.x & 3;
    const float4* gb = (const float4*)(gpart + (size_t)b * KSPLIT * GSZ);

    float sG = 0.0f;
#pragma unroll
    for (int kk = 0; kk < 4; ++kk) {
        const int e4 = quarter * 1024 + kk * 256 + t;
        float4 s = gb[e4];
#pragma unroll
        for (int sl = 1; sl < KSPLIT; ++sl) {
            float4 p = gb[(size_t)sl * (GSZ / 4) + e4];
            s.x += p.x; s.y += p.y; s.z += p.z; s.w += p.w;
        }
        sG += s.x * s.x + s.y * s.y + s.z * s.z + s.w * s.w;
    }
    float sV = 0.0f;
    if (quarter == 0 && t < DIM) {
        float vv = vglob[b * DIM + t];
        sV = vv * vv;
    }
#pragma unroll
    for (int m = 1; m < 64; m <<= 1) {
        sG += __shfl_xor(sG, m);
        sV += __shfl_xor(sV, m);
    }
    __shared__ float wq[8];
    if ((t & 63) == 0) { wq[t >> 6] = sG; wq[4 + (t >> 6)] = sV; }
    __syncthreads();
    if (t == 0) {
        atomicAdd(&acc[0], wq[0] + wq[1] + wq[2] + wq[3]);
        if (quarter == 0) atomicAdd(&acc[1], wq[4] + wq[5] + wq[6] + wq[7]);
    }
}

// ---- k3: result = (sumG2 - 2*sumV2)/(B*S^2) + 1, written as FP32 ----
__global__ void k3_final(const float* __restrict__ acc,
                         float* __restrict__ out) {
    out[0] = (acc[0] - 2.0f * acc[1]) * (1.0f / 67108864.0f) + 1.0f;
}

extern "C" void kernel_launch(void* const* d_in, const int* in_sizes, int n_in,
                              void* d_out, int out_size, void* d_ws, size_t ws_size,
                              hipStream_t stream) {
    const float* X = (const float*)d_in[0];
    float* ws = (float*)d_ws;   // needs ~32.1 MB
    float* vglob = ws + V_OFF;
    float* acc   = ws + ACC_OFF;
    float* gpart = ws + GP_OFF;

    k0_zero<<<(ZTOTAL + 255) / 256, 256, 0, stream>>>(ws);
    k1_gram<<<BATCH * KSPLIT, 256, 0, stream>>>(X, gpart, vglob);
    k2_reduce<<<BATCH * 4, 256, 0, stream>>>(gpart, vglob, acc);
    k3_final<<<1, 1, 0, stream>>>(acc, (float*)d_out);
}